// Round 2
// baseline (581.940 us; speedup 1.0000x reference)
//
#include <hip/hip_runtime.h>
#include <cstdint>

#define B_ 256
#define T_ 512
#define D_ 128
#define U_ 128

typedef _Float16 h2_t __attribute__((ext_vector_type(2)));
typedef _Float16 f16x4 __attribute__((ext_vector_type(4)));
typedef _Float16 f16x8 __attribute__((ext_vector_type(8)));
typedef float f32x4 __attribute__((ext_vector_type(4)));

static __device__ __forceinline__ h2_t as_h2(uint32_t u) {
  return __builtin_bit_cast(h2_t, u);
}
static __device__ __forceinline__ uint32_t pack2(float a, float b) {
  h2_t h;
  h.x = (_Float16)a;
  h.y = (_Float16)b;
  return __builtin_bit_cast(uint32_t, h);
}
static __device__ __forceinline__ float dot2acc(uint32_t a, uint32_t w, float acc) {
#if __has_builtin(__builtin_amdgcn_fdot2)
  return __builtin_amdgcn_fdot2(as_h2(a), as_h2(w), acc, false);
#else
  h2_t ha = as_h2(a), hw = as_h2(w);
  return acc + (float)ha.x * (float)hw.x + (float)ha.y * (float)hw.y;
#endif
}
static __device__ __forceinline__ float sigm(float v) {
  return 1.0f / (1.0f + __expf(-v));
}
static __device__ __forceinline__ float tanh_(float v) {
  return 1.0f - 2.0f / (__expf(2.0f * v) + 1.0f);
}

// quad_perm DPP add: v += lane_xor{1 or 2}(v) within each lane-quad
template <int CTRL>
static __device__ __forceinline__ float dpp_qadd(float v) {
#if __has_builtin(__builtin_amdgcn_mov_dpp)
  int s = __builtin_amdgcn_mov_dpp(__builtin_bit_cast(int, v), CTRL, 0xF, 0xF, true);
  return v + __builtin_bit_cast(float, s);
#else
  return v + __shfl_xor(v, (CTRL == 0xB1) ? 1 : 2, 64);
#endif
}

// ---------------- kernel 0: Wt[col][k] f16 = W[k][col], k<128 (x-part) -------
__global__ __launch_bounds__(256) void wt_kernel(const float* __restrict__ W,
                                                 _Float16* __restrict__ Wt) {
  int id = blockIdx.x * 256 + threadIdx.x;  // 65536 = 512 cols x 128 k
  int j = id >> 7, k = id & 127;
  Wt[j * 128 + k] = (_Float16)W[k * 512 + j];
}

// ---------------- kernel A: gx[row][col] = x[row][:] @ Wx  (f16 out) ---------
// row = b*T + t (131072 rows), col = g*128 + c (natural W column order).
__global__ __launch_bounds__(256, 2) void gx_kernel(const float* __restrict__ x,
                                                    const _Float16* __restrict__ Wt,
                                                    _Float16* __restrict__ gx) {
  __shared__ __align__(16) _Float16 As[64 * 136];  // 64 rows x 128 f16, +8 pad
  const int tid = threadIdx.x;
  const int w = tid >> 6, l = tid & 63;
  const size_t rowBase = (size_t)blockIdx.x * 64;

  // stage A tile (f32 -> f16), fully coalesced float4 loads
  const float4* xs = reinterpret_cast<const float4*>(x + rowBase * 128);
#pragma unroll
  for (int n = 0; n < 8; ++n) {
    int idx4 = tid + 256 * n;
    float4 v = xs[idx4];
    int f = idx4 * 4;
    int r = f >> 7, cc = f & 127;
    f16x4 p;
    p.x = (_Float16)v.x; p.y = (_Float16)v.y;
    p.z = (_Float16)v.z; p.w = (_Float16)v.w;
    *reinterpret_cast<f16x4*>(&As[r * 136 + cc]) = p;
  }
  __syncthreads();

  // hoist all A fragments: rows 16*rt+(l&15), k = 32*kk + 8*(l>>4)
  f16x8 af[4][4];
#pragma unroll
  for (int rt = 0; rt < 4; ++rt)
#pragma unroll
    for (int kk = 0; kk < 4; ++kk)
      af[rt][kk] = *reinterpret_cast<const f16x8*>(
          &As[(16 * rt + (l & 15)) * 136 + 32 * kk + 8 * (l >> 4)]);

  const int colBase = 128 * w;
#pragma unroll 1
  for (int ct = 0; ct < 8; ++ct) {
    const int col = colBase + 16 * ct + (l & 15);
    f32x4 acc[4];
#pragma unroll
    for (int rt = 0; rt < 4; ++rt) acc[rt] = (f32x4){0.f, 0.f, 0.f, 0.f};
    const _Float16* wtc = Wt + (size_t)col * 128 + 8 * (l >> 4);
#pragma unroll
    for (int kk = 0; kk < 4; ++kk) {
      f16x8 bf = *reinterpret_cast<const f16x8*>(wtc + 32 * kk);
#pragma unroll
      for (int rt = 0; rt < 4; ++rt)
        acc[rt] = __builtin_amdgcn_mfma_f32_16x16x32_f16(af[rt][kk], bf, acc[rt], 0, 0, 0);
    }
#pragma unroll
    for (int rt = 0; rt < 4; ++rt) {
      size_t row = rowBase + 16 * rt + 4 * (l >> 4);
#pragma unroll
      for (int j = 0; j < 4; ++j)
        gx[(row + j) * 512 + col] = (_Float16)acc[rt][j];
    }
  }
}

// ---------------- kernel B: the recurrence ----------------------------------
// thread: unit c = tid>>2, k-slice ks = tid&3 over h-part K=128.
// weights (4 gates x 32 k, f16-packed) register-resident; quad-DPP reduction.
static __device__ __forceinline__ void lstm_step(
    int t, int c, int ks, const uint32_t (&wreg)[4][16], const float (&bj)[4],
    uint16_t (&gr)[4], const uint16_t* __restrict__ gxb, float& cst,
    float* __restrict__ ob, const uint32_t* hin, uint32_t* hout) {
  float gxf[4];
#pragma unroll
  for (int g = 0; g < 4; ++g)
    gxf[g] = (float)__builtin_bit_cast(_Float16, gr[g]);
  // prefetch gx for t+2 (2-step latency cover)
  if (t + 2 < T_) {
#pragma unroll
    for (int g = 0; g < 4; ++g) gr[g] = gxb[(size_t)(t + 2) * 512 + g * 128];
  }
  const uint4* hb4 = reinterpret_cast<const uint4*>(hin);
  float a[4] = {0.f, 0.f, 0.f, 0.f};
#pragma unroll
  for (int i = 0; i < 4; ++i) {
    uint4 hv = hb4[ks * 4 + i];
#pragma unroll
    for (int g = 0; g < 4; ++g) {
      a[g] = dot2acc(hv.x, wreg[g][4 * i + 0], a[g]);
      a[g] = dot2acc(hv.y, wreg[g][4 * i + 1], a[g]);
      a[g] = dot2acc(hv.z, wreg[g][4 * i + 2], a[g]);
      a[g] = dot2acc(hv.w, wreg[g][4 * i + 3], a[g]);
    }
  }
#pragma unroll
  for (int g = 0; g < 4; ++g) {
    a[g] = dpp_qadd<0xB1>(a[g]);  // xor 1 within quad
    a[g] = dpp_qadd<0x4E>(a[g]);  // xor 2 within quad
  }
  const float gi = a[0] + gxf[0] + bj[0];
  const float gj = a[1] + gxf[1] + bj[1];
  const float gf = a[2] + gxf[2] + bj[2];
  const float go = a[3] + gxf[3] + bj[3];
  cst = cst * sigm(gf + 1.0f) + sigm(gi) * tanh_(gj);
  const float hh = tanh_(cst) * sigm(go);
  if (ks == 0) {
    ob[(size_t)t * U_ + c] = hh;
    reinterpret_cast<_Float16*>(hout)[c] = (_Float16)hh;
  }
  __syncthreads();
}

__global__ __launch_bounds__(512, 2) void rec_kernel(const float* __restrict__ W,
                                                     const float* __restrict__ bias,
                                                     const uint16_t* __restrict__ gx,
                                                     float* __restrict__ out) {
  __shared__ __align__(16) uint32_t hbuf[2][64];  // h as f16[128], double-buffered
  const int tid = threadIdx.x;
  const int b = blockIdx.x;
  const int c = tid >> 2, ks = tid & 3;

  // register-resident h-part weights: rows 128+32*ks .. +32, cols g*128+c
  uint32_t wreg[4][16];
#pragma unroll
  for (int g = 0; g < 4; ++g) {
    const float* wp = W + (size_t)(128 + 32 * ks) * 512 + g * 128 + c;
#pragma unroll
    for (int m = 0; m < 16; ++m) {
      float w0 = wp[(2 * m) * 512];
      float w1 = wp[(2 * m + 1) * 512];
      wreg[g][m] = pack2(w0, w1);
    }
  }
  float bj[4];
#pragma unroll
  for (int g = 0; g < 4; ++g) bj[g] = bias[g * 128 + c];

  const uint16_t* gxb = gx + (size_t)b * T_ * 512 + c;
  float* ob = out + (size_t)b * T_ * U_;

  if (tid < 64) hbuf[0][tid] = 0u;  // h = 0
  uint16_t g0[4], g1[4];
#pragma unroll
  for (int g = 0; g < 4; ++g) {
    g0[g] = gxb[(size_t)0 * 512 + g * 128];
    g1[g] = gxb[(size_t)1 * 512 + g * 128];
  }
  float cst = 0.0f;
  __syncthreads();

#pragma unroll 1
  for (int t = 0; t < T_; t += 2) {
    lstm_step(t, c, ks, wreg, bj, g0, gxb, cst, ob, &hbuf[0][0], &hbuf[1][0]);
    lstm_step(t + 1, c, ks, wreg, bj, g1, gxb, cst, ob, &hbuf[1][0], &hbuf[0][0]);
  }
}

// ---------------- round-1 fallback (ws too small) ---------------------------
__global__ __launch_bounds__(512, 2) void lstm_fused_kernel(
    const float* __restrict__ x, const float* __restrict__ W,
    const float* __restrict__ bias, float* __restrict__ out) {
  __shared__ __align__(16) uint32_t a_lds[2][128];
  __shared__ float g_lds[512];
  const int tid = threadIdx.x;
  const int b = blockIdx.x;
  uint32_t wreg[128];
#pragma unroll
  for (int q4 = 0; q4 < 32; ++q4) {
    float f[8];
#pragma unroll
    for (int r = 0; r < 8; ++r) f[r] = W[(q4 * 8 + r) * 512 + tid];
#pragma unroll
    for (int rr = 0; rr < 4; ++rr)
      wreg[q4 * 4 + rr] = pack2(f[2 * rr], f[2 * rr + 1]);
  }
  const float bjv = bias[tid];
  const float* xb = x + (size_t)b * (T_ * D_);
  float* ob = out + (size_t)b * (T_ * U_);
  if (tid < 32) {
    float4 x4 = reinterpret_cast<const float4*>(xb)[tid];
    reinterpret_cast<uint2*>(&a_lds[0][0])[tid] =
        make_uint2(pack2(x4.x, x4.y), pack2(x4.z, x4.w));
  }
  if (tid >= 64 && tid < 128) a_lds[0][tid] = 0u;
  __syncthreads();
  float c = 0.0f;
  int p = 0;
  for (int t = 0; t < T_; ++t) {
    float4 xp;
    const bool pf = (tid < 32) && (t + 1 < T_);
    if (pf) xp = reinterpret_cast<const float4*>(xb + (t + 1) * D_)[tid];
    const uint4* av = reinterpret_cast<const uint4*>(&a_lds[p][0]);
    float a0 = bjv, a1 = 0.0f, a2 = 0.0f, a3 = 0.0f;
#pragma unroll
    for (int q = 0; q < 32; ++q) {
      uint4 a4 = av[q];
      a0 = dot2acc(a4.x, wreg[4 * q + 0], a0);
      a1 = dot2acc(a4.y, wreg[4 * q + 1], a1);
      a2 = dot2acc(a4.z, wreg[4 * q + 2], a2);
      a3 = dot2acc(a4.w, wreg[4 * q + 3], a3);
    }
    g_lds[tid] = (a0 + a1) + (a2 + a3);
    __syncthreads();
    if (tid < 128) {
      const float gi = g_lds[tid];
      const float gj = g_lds[128 + tid];
      const float gf = g_lds[256 + tid];
      const float go = g_lds[384 + tid];
      c = c * sigm(gf + 1.0f) + sigm(gi) * tanh_(gj);
      const float h = tanh_(c) * sigm(go);
      ob[t * U_ + tid] = h;
      reinterpret_cast<_Float16*>(&a_lds[p ^ 1][64])[tid] = (_Float16)h;
    }
    if (pf) {
      reinterpret_cast<uint2*>(&a_lds[p ^ 1][0])[tid] =
          make_uint2(pack2(xp.x, xp.y), pack2(xp.z, xp.w));
    }
    __syncthreads();
    p ^= 1;
  }
}

extern "C" void kernel_launch(void* const* d_in, const int* in_sizes, int n_in,
                              void* d_out, int out_size, void* d_ws, size_t ws_size,
                              hipStream_t stream) {
  (void)in_sizes; (void)n_in; (void)out_size;
  const float* x = (const float*)d_in[0];
  const float* W = (const float*)d_in[1];
  const float* b = (const float*)d_in[2];
  float* out = (float*)d_out;

  const size_t WT_BYTES = (size_t)512 * 128 * 2;            // 131 KB
  const size_t GX_BYTES = (size_t)B_ * T_ * 512 * 2;        // 134.2 MB
  if (ws_size >= WT_BYTES + GX_BYTES) {
    _Float16* wt = (_Float16*)d_ws;
    _Float16* gx = (_Float16*)((char*)d_ws + WT_BYTES);
    wt_kernel<<<256, 256, 0, stream>>>(W, wt);
    gx_kernel<<<2048, 256, 0, stream>>>(x, wt, gx);
    rec_kernel<<<256, 512, 0, stream>>>(W, b, (const uint16_t*)gx, out);
  } else {
    lstm_fused_kernel<<<256, 512, 0, stream>>>(x, W, b, out);
  }
}

// Round 3
// 385.396 us; speedup vs baseline: 1.5100x; 1.5100x over previous
//
#include <hip/hip_runtime.h>
#include <cstdint>

#define B_ 256
#define T_ 512
#define D_ 128
#define U_ 128

typedef _Float16 h2_t __attribute__((ext_vector_type(2)));
typedef _Float16 f16x4 __attribute__((ext_vector_type(4)));
typedef _Float16 f16x8 __attribute__((ext_vector_type(8)));
typedef float f32x4 __attribute__((ext_vector_type(4)));

static __device__ __forceinline__ h2_t as_h2(uint32_t u) {
  return __builtin_bit_cast(h2_t, u);
}
static __device__ __forceinline__ uint32_t pack2(float a, float b) {
  h2_t h;
  h.x = (_Float16)a;
  h.y = (_Float16)b;
  return __builtin_bit_cast(uint32_t, h);
}
static __device__ __forceinline__ float dot2acc(uint32_t a, uint32_t w, float acc) {
#if __has_builtin(__builtin_amdgcn_fdot2)
  return __builtin_amdgcn_fdot2(as_h2(a), as_h2(w), acc, false);
#else
  h2_t ha = as_h2(a), hw = as_h2(w);
  return acc + (float)ha.x * (float)hw.x + (float)ha.y * (float)hw.y;
#endif
}

// ---- raw transcendental helpers (avoid div-fixup sequences) ----------------
static __device__ __forceinline__ float fexp2(float x) {
#if __has_builtin(__builtin_amdgcn_exp2f)
  return __builtin_amdgcn_exp2f(x);
#else
  return __exp2f(x);
#endif
}
static __device__ __forceinline__ float frcp(float x) {
#if __has_builtin(__builtin_amdgcn_rcpf)
  return __builtin_amdgcn_rcpf(x);
#else
  return __frcp_rn(x);
#endif
}
#define LOG2E_ 1.44269504f
static __device__ __forceinline__ float sigm(float v) {
  return frcp(1.0f + fexp2(-LOG2E_ * v));  // mul, exp, add, rcp
}
static __device__ __forceinline__ float tanh_(float v) {
  // tanh(x) = 2*sigmoid(2x) - 1; exp2(-inf)->0 gives correct +/-1 limits
  float r = frcp(1.0f + fexp2(-2.0f * LOG2E_ * v));
  return __builtin_fmaf(2.0f, r, -1.0f);  // mul, exp, add, rcp, fma
}

// quad_perm DPP add: v += lane_xor{1 or 2}(v) within each lane-quad
template <int CTRL>
static __device__ __forceinline__ float dpp_qadd(float v) {
#if __has_builtin(__builtin_amdgcn_mov_dpp)
  int s = __builtin_amdgcn_mov_dpp(__builtin_bit_cast(int, v), CTRL, 0xF, 0xF, true);
  return v + __builtin_bit_cast(float, s);
#else
  return v + __shfl_xor(v, (CTRL == 0xB1) ? 1 : 2, 64);
#endif
}

// ---------------- kernel 0: Wt[col][k] f16 = W[k][col], k<128 (x-part) ------
__global__ __launch_bounds__(256) void wt_kernel(const float* __restrict__ W,
                                                 _Float16* __restrict__ Wt) {
  int id = blockIdx.x * 256 + threadIdx.x;  // 65536 = 512 cols x 128 k
  int j = id >> 7, k = id & 127;
  Wt[j * 128 + k] = (_Float16)W[k * 512 + j];
}

// ---------------- kernel A: gx[row][col] = x[row][:] @ Wx + bias' (f16) -----
// row = b*T + t (131072 rows), col = g*128 + c. bias' includes forget +1.0.
__global__ __launch_bounds__(256, 2) void gx_kernel(const float* __restrict__ x,
                                                    const _Float16* __restrict__ Wt,
                                                    const float* __restrict__ bias,
                                                    _Float16* __restrict__ gx) {
  __shared__ __align__(16) _Float16 As[64 * 136];  // 64 rows x 128 f16, +8 pad
  const int tid = threadIdx.x;
  const int w = tid >> 6, l = tid & 63;
  const size_t rowBase = (size_t)blockIdx.x * 64;

  const float4* xs = reinterpret_cast<const float4*>(x + rowBase * 128);
#pragma unroll
  for (int n = 0; n < 8; ++n) {
    int idx4 = tid + 256 * n;
    float4 v = xs[idx4];
    int f = idx4 * 4;
    int r = f >> 7, cc = f & 127;
    f16x4 p;
    p.x = (_Float16)v.x; p.y = (_Float16)v.y;
    p.z = (_Float16)v.z; p.w = (_Float16)v.w;
    *reinterpret_cast<f16x4*>(&As[r * 136 + cc]) = p;
  }
  __syncthreads();

  f16x8 af[4][4];
#pragma unroll
  for (int rt = 0; rt < 4; ++rt)
#pragma unroll
    for (int kk = 0; kk < 4; ++kk)
      af[rt][kk] = *reinterpret_cast<const f16x8*>(
          &As[(16 * rt + (l & 15)) * 136 + 32 * kk + 8 * (l >> 4)]);

  const int colBase = 128 * w;
#pragma unroll 1
  for (int ct = 0; ct < 8; ++ct) {
    const int col = colBase + 16 * ct + (l & 15);
    const float bb = bias[col] + ((col >= 256 && col < 384) ? 1.0f : 0.0f);
    f32x4 acc[4];
#pragma unroll
    for (int rt = 0; rt < 4; ++rt) acc[rt] = (f32x4){0.f, 0.f, 0.f, 0.f};
    const _Float16* wtc = Wt + (size_t)col * 128 + 8 * (l >> 4);
#pragma unroll
    for (int kk = 0; kk < 4; ++kk) {
      f16x8 bf = *reinterpret_cast<const f16x8*>(wtc + 32 * kk);
#pragma unroll
      for (int rt = 0; rt < 4; ++rt)
        acc[rt] = __builtin_amdgcn_mfma_f32_16x16x32_f16(af[rt][kk], bf, acc[rt], 0, 0, 0);
    }
#pragma unroll
    for (int rt = 0; rt < 4; ++rt) {
      size_t row = rowBase + 16 * rt + 4 * (l >> 4);
#pragma unroll
      for (int j = 0; j < 4; ++j)
        gx[(row + j) * 512 + col] = (_Float16)(acc[rt][j] + bb);
    }
  }
}

// ---------------- kernel B: the recurrence ----------------------------------
// thread: unit c = tid>>2, k-slice ks = tid&3 over h-part K=128.
// gx (with bias folded) prefetched in 4-step chunks, 16 const-offset loads.
static __device__ __forceinline__ void step_t(
    int t, int c, int ks, const uint32_t (&wreg)[4][16], const uint16_t (&g4)[4],
    float& cst, float* __restrict__ ob,
    const uint32_t* __restrict__ hin, uint32_t* __restrict__ hout) {
  const uint4* hb4 = reinterpret_cast<const uint4*>(hin) + ks * 4;
  uint4 h0 = hb4[0], h1 = hb4[1], h2 = hb4[2], h3 = hb4[3];

  float a[4] = {0.f, 0.f, 0.f, 0.f};
#pragma unroll
  for (int g = 0; g < 4; ++g) {
    a[g] = dot2acc(h0.x, wreg[g][0], a[g]);
    a[g] = dot2acc(h0.y, wreg[g][1], a[g]);
    a[g] = dot2acc(h0.z, wreg[g][2], a[g]);
    a[g] = dot2acc(h0.w, wreg[g][3], a[g]);
    a[g] = dot2acc(h1.x, wreg[g][4], a[g]);
    a[g] = dot2acc(h1.y, wreg[g][5], a[g]);
    a[g] = dot2acc(h1.z, wreg[g][6], a[g]);
    a[g] = dot2acc(h1.w, wreg[g][7], a[g]);
    a[g] = dot2acc(h2.x, wreg[g][8], a[g]);
    a[g] = dot2acc(h2.y, wreg[g][9], a[g]);
    a[g] = dot2acc(h2.z, wreg[g][10], a[g]);
    a[g] = dot2acc(h2.w, wreg[g][11], a[g]);
    a[g] = dot2acc(h3.x, wreg[g][12], a[g]);
    a[g] = dot2acc(h3.y, wreg[g][13], a[g]);
    a[g] = dot2acc(h3.z, wreg[g][14], a[g]);
    a[g] = dot2acc(h3.w, wreg[g][15], a[g]);
  }
#pragma unroll
  for (int g = 0; g < 4; ++g) {
    a[g] = dpp_qadd<0xB1>(a[g]);
    a[g] = dpp_qadd<0x4E>(a[g]);
    a[g] += (float)__builtin_bit_cast(_Float16, g4[g]);
  }
  // gate order i, j, f, o; bias (+1 forget) already folded into gx
  cst = cst * sigm(a[2]) + sigm(a[0]) * tanh_(a[1]);
  const float hh = tanh_(cst) * sigm(a[3]);
  if (ks == 0) {
    ob[(size_t)t * U_ + c] = hh;
    reinterpret_cast<_Float16*>(hout)[c] = (_Float16)hh;
  }
  __syncthreads();
}

__global__ __launch_bounds__(512, 2) void rec_kernel(const float* __restrict__ W,
                                                     const uint16_t* __restrict__ gx,
                                                     float* __restrict__ out) {
  __shared__ __align__(16) uint32_t hbuf[2][64];  // h as f16[128], double-buffered
  const int tid = threadIdx.x;
  const int b = blockIdx.x;
  const int c = tid >> 2, ks = tid & 3;

  uint32_t wreg[4][16];
#pragma unroll
  for (int g = 0; g < 4; ++g) {
    const float* wp = W + (size_t)(128 + 32 * ks) * 512 + g * 128 + c;
#pragma unroll
    for (int m = 0; m < 16; ++m)
      wreg[g][m] = pack2(wp[(2 * m) * 512], wp[(2 * m + 1) * 512]);
  }

  const uint16_t* gxb = gx + (size_t)b * T_ * 512 + c;
  float* ob = out + (size_t)b * T_ * U_;

  if (tid < 64) hbuf[0][tid] = 0u;  // h = 0

  // 4-step gx chunks: 16 const-offset ushort loads per chunk
  uint16_t gA[4][4], gB[4][4];
#define LOAD_CHUNK(dst, baseT)                                        \
  {                                                                   \
    const uint16_t* _p = gxb + (size_t)(baseT) * 512;                 \
    _Pragma("unroll") for (int _dt = 0; _dt < 4; ++_dt)               \
        _Pragma("unroll") for (int _g = 0; _g < 4; ++_g)              \
            dst[_dt][_g] = _p[_dt * 512 + _g * 128];                  \
  }
  LOAD_CHUNK(gA, 0)
  LOAD_CHUNK(gB, 4)

  float cst = 0.0f;
  __syncthreads();

#pragma unroll 1
  for (int tt = 0; tt < T_; tt += 8) {
    uint16_t t0[4], t1[4], t2[4], t3[4];
#pragma unroll
    for (int g = 0; g < 4; ++g) { t0[g] = gA[0][g]; t1[g] = gA[1][g]; t2[g] = gA[2][g]; t3[g] = gA[3][g]; }
    step_t(tt + 0, c, ks, wreg, t0, cst, ob, &hbuf[0][0], &hbuf[1][0]);
    step_t(tt + 1, c, ks, wreg, t1, cst, ob, &hbuf[1][0], &hbuf[0][0]);
    step_t(tt + 2, c, ks, wreg, t2, cst, ob, &hbuf[0][0], &hbuf[1][0]);
    step_t(tt + 3, c, ks, wreg, t3, cst, ob, &hbuf[1][0], &hbuf[0][0]);
    if (tt + 8 < T_) LOAD_CHUNK(gA, tt + 8)
#pragma unroll
    for (int g = 0; g < 4; ++g) { t0[g] = gB[0][g]; t1[g] = gB[1][g]; t2[g] = gB[2][g]; t3[g] = gB[3][g]; }
    step_t(tt + 4, c, ks, wreg, t0, cst, ob, &hbuf[0][0], &hbuf[1][0]);
    step_t(tt + 5, c, ks, wreg, t1, cst, ob, &hbuf[1][0], &hbuf[0][0]);
    step_t(tt + 6, c, ks, wreg, t2, cst, ob, &hbuf[0][0], &hbuf[1][0]);
    step_t(tt + 7, c, ks, wreg, t3, cst, ob, &hbuf[1][0], &hbuf[0][0]);
    if (tt + 12 < T_) LOAD_CHUNK(gB, tt + 12)
  }
#undef LOAD_CHUNK
}

extern "C" void kernel_launch(void* const* d_in, const int* in_sizes, int n_in,
                              void* d_out, int out_size, void* d_ws, size_t ws_size,
                              hipStream_t stream) {
  (void)in_sizes; (void)n_in; (void)out_size;
  const float* x = (const float*)d_in[0];
  const float* W = (const float*)d_in[1];
  const float* b = (const float*)d_in[2];
  float* out = (float*)d_out;

  const size_t WT_BYTES = (size_t)512 * 128 * 2;      // 131 KB
  const size_t GX_BYTES = (size_t)B_ * T_ * 512 * 2;  // 134.2 MB
  if (ws_size >= WT_BYTES + GX_BYTES) {
    _Float16* wt = (_Float16*)d_ws;
    _Float16* gxp = (_Float16*)((char*)d_ws + WT_BYTES);
    wt_kernel<<<256, 256, 0, stream>>>(W, wt);
    gx_kernel<<<2048, 256, 0, stream>>>(x, wt, b, gxp);
    rec_kernel<<<256, 512, 0, stream>>>(W, (const uint16_t*)gxp, out);
  }
}

// Round 4
// 295.636 us; speedup vs baseline: 1.9684x; 1.3036x over previous
//
#include <hip/hip_runtime.h>
#include <cstdint>

#define B_ 256
#define T_ 512
#define D_ 128
#define U_ 128

typedef _Float16 h2_t __attribute__((ext_vector_type(2)));
typedef _Float16 f16x4 __attribute__((ext_vector_type(4)));
typedef _Float16 f16x8 __attribute__((ext_vector_type(8)));
typedef float f32x4 __attribute__((ext_vector_type(4)));

static __device__ __forceinline__ uint32_t pack2(float a, float b) {
  h2_t h;
  h.x = (_Float16)a;
  h.y = (_Float16)b;
  return __builtin_bit_cast(uint32_t, h);
}
static __device__ __forceinline__ h2_t as_h2(uint32_t u) {
  return __builtin_bit_cast(h2_t, u);
}
static __device__ __forceinline__ float dot2acc(uint32_t a, uint32_t w, float acc) {
#if __has_builtin(__builtin_amdgcn_fdot2)
  return __builtin_amdgcn_fdot2(as_h2(a), as_h2(w), acc, false);
#else
  h2_t ha = as_h2(a), hw = as_h2(w);
  return acc + (float)ha.x * (float)hw.x + (float)ha.y * (float)hw.y;
#endif
}

// ---- raw transcendentals (no div-fixup sequences) --------------------------
static __device__ __forceinline__ float fexp2(float x) {
#if __has_builtin(__builtin_amdgcn_exp2f)
  return __builtin_amdgcn_exp2f(x);
#else
  return __exp2f(x);
#endif
}
static __device__ __forceinline__ float frcp(float x) {
#if __has_builtin(__builtin_amdgcn_rcpf)
  return __builtin_amdgcn_rcpf(x);
#else
  return __frcp_rn(x);
#endif
}
#define LOG2E_ 1.44269504f
static __device__ __forceinline__ float sigm(float v) {
  return frcp(1.0f + fexp2(-LOG2E_ * v));
}
static __device__ __forceinline__ float tanh_(float v) {
  float r = frcp(1.0f + fexp2(-2.0f * LOG2E_ * v));
  return __builtin_fmaf(2.0f, r, -1.0f);
}

// ---------------- kernel 0: transpose W to f16 [col][k] ---------------------
// Wtx[col][k] = W[k][col]        (k < 128, x-part, for gx GEMM B-frags)
// Wth[col][k] = W[128+k][col]    (k < 128, h-part, for rec B-frags)
__global__ __launch_bounds__(256) void wt_kernel(const float* __restrict__ W,
                                                 _Float16* __restrict__ Wtx,
                                                 _Float16* __restrict__ Wth) {
  int id = blockIdx.x * 256 + threadIdx.x;  // 131072 = 512 cols x 256 k
  int col = id >> 8, k = id & 255;
  _Float16 v = (_Float16)W[(size_t)k * 512 + col];
  if (k < 128) Wtx[col * 128 + k] = v;
  else Wth[col * 128 + (k - 128)] = v;
}

// ---------------- kernel A: gx2 = x @ Wx + bias' (f16, gate-interleaved) ----
// gx2[row][u][g]: row = b*T+t, u = unit (0..127), g = gate (i,j,f,o).
// bias' includes forget +1.0.
__global__ __launch_bounds__(256, 2) void gx_kernel(const float* __restrict__ x,
                                                    const _Float16* __restrict__ Wt,
                                                    const float* __restrict__ bias,
                                                    _Float16* __restrict__ gx) {
  __shared__ __align__(16) _Float16 As[64 * 136];  // 64 rows x 128 f16, +8 pad
  const int tid = threadIdx.x;
  const int w = tid >> 6, l = tid & 63;
  const size_t rowBase = (size_t)blockIdx.x * 64;

  const float4* xs = reinterpret_cast<const float4*>(x + rowBase * 128);
#pragma unroll
  for (int n = 0; n < 8; ++n) {
    int idx4 = tid + 256 * n;
    float4 v = xs[idx4];
    int f = idx4 * 4;
    int r = f >> 7, cc = f & 127;
    f16x4 p;
    p.x = (_Float16)v.x; p.y = (_Float16)v.y;
    p.z = (_Float16)v.z; p.w = (_Float16)v.w;
    *reinterpret_cast<f16x4*>(&As[r * 136 + cc]) = p;
  }
  __syncthreads();

  f16x8 af[4][4];
#pragma unroll
  for (int rt = 0; rt < 4; ++rt)
#pragma unroll
    for (int kk = 0; kk < 4; ++kk)
      af[rt][kk] = *reinterpret_cast<const f16x8*>(
          &As[(16 * rt + (l & 15)) * 136 + 32 * kk + 8 * (l >> 4)]);

  const int colBase = 128 * w;  // w = gate index g for this wave
#pragma unroll 1
  for (int ct = 0; ct < 8; ++ct) {
    const int col = colBase + 16 * ct + (l & 15);
    const float bb = bias[col] + ((col >= 256 && col < 384) ? 1.0f : 0.0f);
    f32x4 acc[4];
#pragma unroll
    for (int rt = 0; rt < 4; ++rt) acc[rt] = (f32x4){0.f, 0.f, 0.f, 0.f};
    const _Float16* wtc = Wt + (size_t)col * 128 + 8 * (l >> 4);
#pragma unroll
    for (int kk = 0; kk < 4; ++kk) {
      f16x8 bf = *reinterpret_cast<const f16x8*>(wtc + 32 * kk);
#pragma unroll
      for (int rt = 0; rt < 4; ++rt)
        acc[rt] = __builtin_amdgcn_mfma_f32_16x16x32_f16(af[rt][kk], bf, acc[rt], 0, 0, 0);
    }
    const int u = col & 127, g = col >> 7;
#pragma unroll
    for (int rt = 0; rt < 4; ++rt) {
      size_t row = rowBase + 16 * rt + 4 * (l >> 4);
#pragma unroll
      for (int j = 0; j < 4; ++j)
        gx[(row + j) * 512 + u * 4 + g] = (_Float16)(acc[rt][j] + bb);
    }
  }
}

// ---------------- kernel B: MFMA recurrence ---------------------------------
// Wave w owns cols {128g + 16w + (l&15), g=0..3}. Since all lanes in an
// l>>4 group read the SAME h fragment, all 16 MFMA output rows are equal:
// every lane holds gate g of unit u = 16w+(l&15) in acc_g[0]. Pointwise
// LSTM update is fully in-lane; one barrier per step; LDS = 512 B.
__global__ __launch_bounds__(512, 2) void rec_kernel(
    const _Float16* __restrict__ Wth,  // [512 cols][128 k] f16
    const uint16_t* __restrict__ gx2,  // [B*T][128][4] f16 bits
    float* __restrict__ out) {
  __shared__ __align__(16) _Float16 hbuf[2][128];
  const int tid = threadIdx.x;
  const int b = blockIdx.x;
  const int w = tid >> 6, l = tid & 63;
  const int lq = l >> 4;
  const int u = 16 * w + (l & 15);
  const bool wr = (lq == 0);

  // B fragments: bw[g][kk] = Wth[col=128g+u][k=32kk+8lq .. +8]
  f16x8 bw[4][4];
#pragma unroll
  for (int g = 0; g < 4; ++g) {
    const _Float16* wc = Wth + (size_t)(128 * g + u) * 128 + 8 * lq;
#pragma unroll
    for (int kk = 0; kk < 4; ++kk)
      bw[g][kk] = *reinterpret_cast<const f16x8*>(wc + 32 * kk);
  }

  const uint16_t* gxb = gx2 + (size_t)b * T_ * 512 + 4 * u;
  float* ob = out + (size_t)b * T_ * U_ + u;

  if (tid < 64) reinterpret_cast<uint32_t*>(&hbuf[0][0])[tid] = 0u;  // h = 0

  const f32x4 Z = {0.f, 0.f, 0.f, 0.f};
  float cst = 0.0f;

#define GXLD(idx) \
  (*reinterpret_cast<const f16x4*>(gxb + (size_t)((idx) < T_ ? (idx) : (T_ - 1)) * 512))

  f16x4 gp0 = GXLD(0), gp1 = GXLD(1), gp2 = GXLD(2), gp3 = GXLD(3);
  __syncthreads();

#define STEP(tt, p, gv)                                                          \
  {                                                                              \
    const _Float16* hb = &hbuf[p][0];                                            \
    f16x8 a0 = *reinterpret_cast<const f16x8*>(hb + 8 * lq);                     \
    f16x8 a1 = *reinterpret_cast<const f16x8*>(hb + 32 + 8 * lq);                \
    f16x8 a2 = *reinterpret_cast<const f16x8*>(hb + 64 + 8 * lq);                \
    f16x8 a3 = *reinterpret_cast<const f16x8*>(hb + 96 + 8 * lq);                \
    f32x4 c0 = __builtin_amdgcn_mfma_f32_16x16x32_f16(a0, bw[0][0], Z, 0, 0, 0); \
    f32x4 c1 = __builtin_amdgcn_mfma_f32_16x16x32_f16(a0, bw[1][0], Z, 0, 0, 0); \
    f32x4 c2 = __builtin_amdgcn_mfma_f32_16x16x32_f16(a0, bw[2][0], Z, 0, 0, 0); \
    f32x4 c3 = __builtin_amdgcn_mfma_f32_16x16x32_f16(a0, bw[3][0], Z, 0, 0, 0); \
    c0 = __builtin_amdgcn_mfma_f32_16x16x32_f16(a1, bw[0][1], c0, 0, 0, 0);      \
    c1 = __builtin_amdgcn_mfma_f32_16x16x32_f16(a1, bw[1][1], c1, 0, 0, 0);      \
    c2 = __builtin_amdgcn_mfma_f32_16x16x32_f16(a1, bw[2][1], c2, 0, 0, 0);      \
    c3 = __builtin_amdgcn_mfma_f32_16x16x32_f16(a1, bw[3][1], c3, 0, 0, 0);      \
    c0 = __builtin_amdgcn_mfma_f32_16x16x32_f16(a2, bw[0][2], c0, 0, 0, 0);      \
    c1 = __builtin_amdgcn_mfma_f32_16x16x32_f16(a2, bw[1][2], c1, 0, 0, 0);      \
    c2 = __builtin_amdgcn_mfma_f32_16x16x32_f16(a2, bw[2][2], c2, 0, 0, 0);      \
    c3 = __builtin_amdgcn_mfma_f32_16x16x32_f16(a2, bw[3][2], c3, 0, 0, 0);      \
    c0 = __builtin_amdgcn_mfma_f32_16x16x32_f16(a3, bw[0][3], c0, 0, 0, 0);      \
    c1 = __builtin_amdgcn_mfma_f32_16x16x32_f16(a3, bw[1][3], c1, 0, 0, 0);      \
    c2 = __builtin_amdgcn_mfma_f32_16x16x32_f16(a3, bw[2][3], c2, 0, 0, 0);      \
    c3 = __builtin_amdgcn_mfma_f32_16x16x32_f16(a3, bw[3][3], c3, 0, 0, 0);      \
    const float gi = c0[0] + (float)(gv).x;                                      \
    const float gj = c1[0] + (float)(gv).y;                                      \
    const float gf = c2[0] + (float)(gv).z;                                      \
    const float go = c3[0] + (float)(gv).w;                                      \
    cst = cst * sigm(gf) + sigm(gi) * tanh_(gj);                                 \
    const float hh = tanh_(cst) * sigm(go);                                      \
    if (wr) {                                                                    \
      ob[(size_t)(tt) * U_] = hh;                                                \
      hbuf[(p) ^ 1][u] = (_Float16)hh;                                           \
    }                                                                            \
    __syncthreads();                                                             \
  }

#pragma unroll 1
  for (int t = 0; t < T_; t += 4) {
    STEP(t + 0, 0, gp0)
    gp0 = GXLD(t + 4);
    STEP(t + 1, 1, gp1)
    gp1 = GXLD(t + 5);
    STEP(t + 2, 0, gp2)
    gp2 = GXLD(t + 6);
    STEP(t + 3, 1, gp3)
    gp3 = GXLD(t + 7);
  }
#undef STEP
#undef GXLD
}

// ---------------- round-1 fallback (ws too small) ---------------------------
__global__ __launch_bounds__(512, 2) void lstm_fused_kernel(
    const float* __restrict__ x, const float* __restrict__ W,
    const float* __restrict__ bias, float* __restrict__ out) {
  __shared__ __align__(16) uint32_t a_lds[2][128];
  __shared__ float g_lds[512];
  const int tid = threadIdx.x;
  const int b = blockIdx.x;
  uint32_t wreg[128];
#pragma unroll
  for (int q4 = 0; q4 < 32; ++q4) {
    float f[8];
#pragma unroll
    for (int r = 0; r < 8; ++r) f[r] = W[(q4 * 8 + r) * 512 + tid];
#pragma unroll
    for (int rr = 0; rr < 4; ++rr)
      wreg[q4 * 4 + rr] = pack2(f[2 * rr], f[2 * rr + 1]);
  }
  const float bjv = bias[tid];
  const float* xb = x + (size_t)b * (T_ * D_);
  float* ob = out + (size_t)b * (T_ * U_);
  if (tid < 32) {
    float4 x4 = reinterpret_cast<const float4*>(xb)[tid];
    reinterpret_cast<uint2*>(&a_lds[0][0])[tid] =
        make_uint2(pack2(x4.x, x4.y), pack2(x4.z, x4.w));
  }
  if (tid >= 64 && tid < 128) a_lds[0][tid] = 0u;
  __syncthreads();
  float c = 0.0f;
  int p = 0;
  for (int t = 0; t < T_; ++t) {
    float4 xp;
    const bool pf = (tid < 32) && (t + 1 < T_);
    if (pf) xp = reinterpret_cast<const float4*>(xb + (t + 1) * D_)[tid];
    const uint4* av = reinterpret_cast<const uint4*>(&a_lds[p][0]);
    float a0 = bjv, a1 = 0.0f, a2 = 0.0f, a3 = 0.0f;
#pragma unroll
    for (int q = 0; q < 32; ++q) {
      uint4 a4 = av[q];
      a0 = dot2acc(a4.x, wreg[4 * q + 0], a0);
      a1 = dot2acc(a4.y, wreg[4 * q + 1], a1);
      a2 = dot2acc(a4.z, wreg[4 * q + 2], a2);
      a3 = dot2acc(a4.w, wreg[4 * q + 3], a3);
    }
    g_lds[tid] = (a0 + a1) + (a2 + a3);
    __syncthreads();
    if (tid < 128) {
      const float gi = g_lds[tid];
      const float gj = g_lds[128 + tid];
      const float gf = g_lds[256 + tid];
      const float go = g_lds[384 + tid];
      c = c * sigm(gf + 1.0f) + sigm(gi) * tanh_(gj);
      const float h = tanh_(c) * sigm(go);
      ob[t * U_ + tid] = h;
      reinterpret_cast<_Float16*>(&a_lds[p ^ 1][64])[tid] = (_Float16)h;
    }
    if (pf) {
      reinterpret_cast<uint2*>(&a_lds[p ^ 1][0])[tid] =
          make_uint2(pack2(xp.x, xp.y), pack2(xp.z, xp.w));
    }
    __syncthreads();
    p ^= 1;
  }
}

extern "C" void kernel_launch(void* const* d_in, const int* in_sizes, int n_in,
                              void* d_out, int out_size, void* d_ws, size_t ws_size,
                              hipStream_t stream) {
  (void)in_sizes; (void)n_in; (void)out_size;
  const float* x = (const float*)d_in[0];
  const float* W = (const float*)d_in[1];
  const float* b = (const float*)d_in[2];
  float* out = (float*)d_out;

  const size_t WTX_BYTES = (size_t)512 * 128 * 2;     // 131 KB
  const size_t WTH_BYTES = (size_t)512 * 128 * 2;     // 131 KB
  const size_t GX_BYTES = (size_t)B_ * T_ * 512 * 2;  // 134.2 MB
  if (ws_size >= WTX_BYTES + WTH_BYTES + GX_BYTES) {
    _Float16* wtx = (_Float16*)d_ws;
    _Float16* wth = (_Float16*)((char*)d_ws + WTX_BYTES);
    _Float16* gxp = (_Float16*)((char*)d_ws + WTX_BYTES + WTH_BYTES);
    wt_kernel<<<512, 256, 0, stream>>>(W, wtx, wth);
    gx_kernel<<<2048, 256, 0, stream>>>(x, wtx, b, gxp);
    rec_kernel<<<256, 512, 0, stream>>>(wth, (const uint16_t*)gxp, out);
  } else {
    lstm_fused_kernel<<<256, 512, 0, stream>>>(x, W, b, out);
  }
}